// Round 4
// baseline (496.635 us; speedup 1.0000x reference)
//
#include <hip/hip_runtime.h>

#define NRUNS  128
#define TSTEPS 2048
#define NAG    16
#define SENS   7
#define HID    22

typedef float float2v __attribute__((ext_vector_type(2)));

// DPP move, bound_ctrl=1 (invalid source lanes -> 0).
// 0x101 row_shl:1, 0x111 row_shr:1, 0x128 row_ror:8 (== lane^8 within 16-row).
template<int CTRL>
__device__ __forceinline__ float dpp_mov(float v) {
    return __int_as_float(__builtin_amdgcn_update_dpp(
        0, __float_as_int(v), CTRL, 0xf, 0xf, true));
}

// Sum over the 4 hidden-unit slices of this lane's group:
// + v[l^8] (row_ror:8 butterfly) then + v[l^32] via v_permlane32_swap_b32.
// r[0]+r[1] == v[l] + v[l^32] under either swap-direction convention.
__device__ __forceinline__ float grp_sum(float v) {
    v += dpp_mov<0x128>(v);
    unsigned u = __float_as_uint(v);
    auto r = __builtin_amdgcn_permlane32_swap(u, u, false, false);
    return __uint_as_float(r[0]) + __uint_as_float(r[1]);
}

struct RawBlk { float2v v[2][7]; };                 // 2 pairs x 14 floats
struct XpBlk  { float2v e[2][3]; float2v o[2][3]; };// packed x-parts (6 units/lane)

__global__ void __launch_bounds__(64, 1) comm_net_kernel(
    const float* __restrict__ runs,       // [128][2048][16][7]
    const float* __restrict__ comm_init,  // [128][18]
    const float* __restrict__ W1,         // [22][9]
    const float* __restrict__ b1,         // [22]
    const float* __restrict__ W2,         // [2][22]
    const float* __restrict__ b2,         // [2]
    float* __restrict__ out)              // [128][2048][16]
{
    const int run  = blockIdx.x;
    const int lane = threadIdx.x & 63;
    const int g    = lane & 7;                          // agent group in bits 0-2
    const int sub2 = ((lane >> 3) & 1) | ((lane >> 4) & 2);  // unit slice: bits 3,5
    // bit 4 = redundant replica (both replicas compute identical sums)
    const bool g0 = (g == 0);
    const bool g7 = (g == 7);

    // ---- per-lane weights: units j = sub2*6 .. sub2*6+5, packed in pairs ----
    float2v w1p[3][SENS], b1p[3], wAp[3], wAmp[3], wBp[3], wBmp[3], w20p[3], w21p[3];
#pragma unroll
    for (int u2 = 0; u2 < 3; ++u2) {
#pragma unroll
        for (int h = 0; h < 2; ++h) {
            int j = sub2 * 6 + u2 * 2 + h;
            bool valid = (j < HID);
            int jj = valid ? j : 0;
            float m = valid ? 1.0f : 0.0f;
#pragma unroll
            for (int k = 0; k < SENS; ++k) w1p[u2][k][h] = m * W1[jj * 9 + k];
            float wa = m * W1[jj * 9 + 7];   // weight on comm[i]
            float wb = m * W1[jj * 9 + 8];   // weight on comm[i+2]
            wAp[u2][h]  = wa;
            wAmp[u2][h] = g0 ? 0.f : wa;     // even-substep cross masked at g=0
            wBp[u2][h]  = wb;
            wBmp[u2][h] = g7 ? 0.f : wb;     // odd-substep cross masked at g=7
            b1p[u2][h]  = m * b1[jj];
            w20p[u2][h] = m * W2[jj];
            w21p[u2][h] = m * W2[HID + jj];
        }
    }
    const float b20 = b2[0], b21 = b2[1];

    const float* ci = comm_init + run * (NAG + 2);
    float prevV = ci[2 * g + 2];
    const float initV_e = ci[2 * g + 1];
    const float initV_o = ci[2 * g + 2];

    const float* pr = runs + (size_t)run * TSTEPS * NAG * SENS;
    float*       po = out  + (size_t)run * TSTEPS * NAG;

    // packed x-parts for one pair: e/o[u2] = b1 + W1x . x  (even/odd agent)
    auto xpart_pair = [&](const float2v (&r)[7], float2v (&ae)[3], float2v (&ao)[3]) {
#pragma unroll
        for (int u2 = 0; u2 < 3; ++u2) {
            float2v e = b1p[u2];
            e = w1p[u2][0] * (float2v){r[0].x, r[0].x} + e;
            e = w1p[u2][1] * (float2v){r[0].y, r[0].y} + e;
            e = w1p[u2][2] * (float2v){r[1].x, r[1].x} + e;
            e = w1p[u2][3] * (float2v){r[1].y, r[1].y} + e;
            e = w1p[u2][4] * (float2v){r[2].x, r[2].x} + e;
            e = w1p[u2][5] * (float2v){r[2].y, r[2].y} + e;
            e = w1p[u2][6] * (float2v){r[3].x, r[3].x} + e;
            ae[u2] = e;
            float2v o = b1p[u2];
            o = w1p[u2][0] * (float2v){r[3].y, r[3].y} + o;
            o = w1p[u2][1] * (float2v){r[4].x, r[4].x} + o;
            o = w1p[u2][2] * (float2v){r[4].y, r[4].y} + o;
            o = w1p[u2][3] * (float2v){r[5].x, r[5].x} + o;
            o = w1p[u2][4] * (float2v){r[5].y, r[5].y} + o;
            o = w1p[u2][5] * (float2v){r[6].x, r[6].x} + o;
            o = w1p[u2][6] * (float2v){r[6].y, r[6].y} + o;
            ao[u2] = o;
        }
    };

    // even sub-step: agent 2g. cL = comm[2g] from group g-1 (row_shr:1), cR = own prevV.
    auto substep_even = [&](const float2v (&xe)[3], float& o0out) {
        float cL = dpp_mov<0x111>(prevV);        // lane-1 = (g-1, same slice)
        float2v cL2 = {cL, cL}, pV2 = {prevV, prevV};
        float2v a0 = wAmp[0] * cL2 + (wBp[0] * pV2 + xe[0]);
        float2v a1 = wAmp[1] * cL2 + (wBp[1] * pV2 + xe[1]);
        float2v a2 = wAmp[2] * cL2 + (wBp[2] * pV2 + xe[2]);
        a0.x = fmaxf(a0.x, 0.f); a0.y = fmaxf(a0.y, 0.f);
        a1.x = fmaxf(a1.x, 0.f); a1.y = fmaxf(a1.y, 0.f);
        a2.x = fmaxf(a2.x, 0.f); a2.y = fmaxf(a2.y, 0.f);
        float2v q0 = w20p[0] * a0; q0 = w20p[1] * a1 + q0; q0 = w20p[2] * a2 + q0;
        float2v q1 = w21p[0] * a0; q1 = w21p[1] * a1 + q1; q1 = w21p[2] * a2 + q1;
        o0out = grp_sum(q0.x + q0.y) + b20;
        prevV = grp_sum(q1.x + q1.y) + b21;      // comm[2g+1]
    };
    // odd sub-step: agent 2g+1. cL = own prevV, cR = comm[2g+3] from g+1 (row_shl:1).
    auto substep_odd = [&](const float2v (&xo)[3], float& o0out) {
        float cR = dpp_mov<0x101>(prevV);        // lane+1 = (g+1, same slice)
        float2v cR2 = {cR, cR}, pV2 = {prevV, prevV};
        float2v a0 = wBmp[0] * cR2 + (wAp[0] * pV2 + xo[0]);
        float2v a1 = wBmp[1] * cR2 + (wAp[1] * pV2 + xo[1]);
        float2v a2 = wBmp[2] * cR2 + (wAp[2] * pV2 + xo[2]);
        a0.x = fmaxf(a0.x, 0.f); a0.y = fmaxf(a0.y, 0.f);
        a1.x = fmaxf(a1.x, 0.f); a1.y = fmaxf(a1.y, 0.f);
        a2.x = fmaxf(a2.x, 0.f); a2.y = fmaxf(a2.y, 0.f);
        float2v q0 = w20p[0] * a0; q0 = w20p[1] * a1 + q0; q0 = w20p[2] * a2 + q0;
        float2v q1 = w21p[0] * a0; q1 = w21p[1] * a1 + q1; q1 = w21p[2] * a2 + q1;
        o0out = grp_sum(q0.x + q0.y) + b20;
        prevV = grp_sum(q1.x + q1.y) + b21;      // comm[2g+2]
    };

    // guarded pair for pipeline ramp in/out (15 total — slow path OK)
    auto ramp_pair = [&](int s) {
        int t  = (s >> 1) - g;
        int tc = t < 0 ? 0 : (t > TSTEPS - 1 ? TSTEPS - 1 : t);
        const float2v* xp = (const float2v*)(pr + ((size_t)tc * NAG + 2 * g) * SENS);
        float2v r[7];
#pragma unroll
        for (int k = 0; k < 7; ++k) r[k] = xp[k];
        float2v ae[3], ao[3];
        xpart_pair(r, ae, ao);
        bool inr = (t >= 0) && (t < TSTEPS);
        float o0;
        substep_even(ae, o0);
        if (inr) po[(size_t)t * NAG + 2 * g] = o0;
        prevV = (t < 0) ? initV_e : prevV;
        substep_odd(ao, o0);
        if (inr) po[(size_t)t * NAG + 2 * g + 1] = o0;
        prevV = (t < 0) ? initV_o : prevV;
    };

    // ---- ramp-in: global steps s=0..15 (8 pairs) ----
#pragma unroll 1
    for (int s = 0; s <= 14; s += 2) ramp_pair(s);

    // ---- steady: 2040 pairs = 1020 blocks of 2; t = pair + 8 - g, all in range ----
    const float2v* xv = (const float2v*)(pr + ((size_t)(8 - g) * NAG + 2 * g) * SENS);
    float* oe = po + (size_t)(8 - g) * NAG + 2 * g;

    RawBlk RA, RB;
    XpBlk  P0, P1;

    auto load_blk = [&](RawBlk& R, const float2v* p) {
#pragma unroll
        for (int j = 0; j < 2; ++j)
#pragma unroll
            for (int k = 0; k < 7; ++k)
                R.v[j][k] = p[j * 56 + k];
    };
    auto xpart_blk = [&](XpBlk& P, const RawBlk& R) {
#pragma unroll
        for (int j = 0; j < 2; ++j) xpart_pair(R.v[j], P.e[j], P.o[j]);
    };
    auto process_blk = [&](const XpBlk& P) {
#pragma unroll
        for (int j = 0; j < 2; ++j) {
            float o0;
            substep_even(P.e[j], o0);
            oe[0] = o0;
            substep_odd(P.o[j], o0);
            oe[1] = o0;
            oe += NAG;
        }
    };

    // pipeline fill: P0 = xparts(block0), RB = raws(block1), RA = raws(block2)
    load_blk(RA, xv);
    load_blk(RB, xv + 112);
    xpart_blk(P0, RA);
    load_blk(RA, xv + 2 * 112);

#pragma unroll 1
    for (int bm = 0; bm < 1016; bm += 2) {
        xpart_blk(P1, RB);                             // block bm+1
        load_blk(RB, xv + (size_t)(bm + 3) * 112);
        process_blk(P0);                               // block bm
        xpart_blk(P0, RA);                             // block bm+2
        load_blk(RA, xv + (size_t)(bm + 4) * 112);
        process_blk(P1);                               // block bm+1
    }
    // epilogue: blocks 1016..1019 (loads stay in-bounds)
    xpart_blk(P1, RB);                                 // 1017
    load_blk(RB, xv + (size_t)1019 * 112);
    process_blk(P0);                                   // 1016
    xpart_blk(P0, RA);                                 // 1018
    process_blk(P1);                                   // 1017
    xpart_blk(P1, RB);                                 // 1019
    process_blk(P0);                                   // 1018
    process_blk(P1);                                   // 1019

    // ---- ramp-out: 7 guarded pairs ----
#pragma unroll 1
    for (int s = 2 * TSTEPS; s <= 2 * TSTEPS + 12; s += 2) ramp_pair(s);
}

extern "C" void kernel_launch(void* const* d_in, const int* in_sizes, int n_in,
                              void* d_out, int out_size, void* d_ws, size_t ws_size,
                              hipStream_t stream) {
    const float* runs      = (const float*)d_in[0];
    const float* comm_init = (const float*)d_in[1];
    const float* W1        = (const float*)d_in[2];
    const float* b1        = (const float*)d_in[3];
    const float* W2        = (const float*)d_in[4];
    const float* b2        = (const float*)d_in[5];
    float* out = (float*)d_out;

    dim3 grid(NRUNS), block(64);
    hipLaunchKernelGGL(comm_net_kernel, grid, block, 0, stream,
                       runs, comm_init, W1, b1, W2, b2, out);
}